// Round 9
// baseline (370.509 us; speedup 1.0000x reference)
//
#include <hip/hip_runtime.h>
#include <hip/hip_fp16.h>
#include <math.h>

#define NEG_SLOPE 0.2f
#define LOG2E 1.44269504088896340736f

#if __has_builtin(__builtin_amdgcn_exp2f)
#define EXP2(x) __builtin_amdgcn_exp2f(x)
#else
#define EXP2(x) exp2f(x)
#endif

// in-wave butterfly add via DPP (plain VALU, no DS pipe): validated R5/R6.
#define DPP_ADD(p, ctrl) \
    p += __int_as_float(__builtin_amdgcn_update_dpp(0, __float_as_int(p), ctrl, 0xf, 0xf, true))

typedef __fp16 half4v __attribute__((ext_vector_type(4)));
typedef __fp16 half2v __attribute__((ext_vector_type(2)));
typedef float  f32x4  __attribute__((ext_vector_type(4)));

// fp16 pack/unpack helpers (storage-only fp16; all math fp32)
__device__ __forceinline__ unsigned f2h2(float x, float y) {
    union { unsigned u; __half2 h; } r;
    r.h = __floats2half2_rn(x, y);
    return r.u;
}

// dot2: fp16 pair x fp16 pair + f32 -> f32 (v_dot2_f32_f16)
#if __has_builtin(__builtin_amdgcn_fdot2)
#define FDOT2(a, b, c) __builtin_amdgcn_fdot2((a), (b), (c), false)
#else
__device__ __forceinline__ float FDOT2(half2v a, half2v b, float c) {
    return c + (float)a[0] * (float)b[0] + (float)a[1] * (float)b[1];
}
#endif

// ---------------------------------------------------------------------------
// AtomEncoder + edge histogram (fused). x stored fp16.
// ---------------------------------------------------------------------------
__global__ __launch_bounds__(256) void embed_kernel(
        const int* __restrict__ feat, const float* __restrict__ emb,
        const int* __restrict__ dstE, int* __restrict__ counts,
        __half* __restrict__ x, int N, int E) {
    int gid = blockIdx.x * 256 + threadIdx.x;
    if (gid < E) atomicAdd(&counts[dstE[gid]], 1);

    const int offs[9] = {0, 119, 124, 136, 148, 158, 164, 170, 172};
    int sub  = threadIdx.x >> 6;
    int lane = threadIdx.x & 63;
    int n = __builtin_amdgcn_readfirstlane(blockIdx.x * 4 + sub);
    if (n >= N) return;
    float s = 0.f;
#pragma unroll
    for (int j = 0; j < 9; ++j) {
        int idx = feat[n * 9 + j] + offs[j];
        s += emb[idx * 64 + lane];
    }
    x[(size_t)n * 64 + lane] = __float2half(s);
}

// ---------------------------------------------------------------------------
// Dual GEMM (MFMA), exact R4 configuration -- best measured. FROZEN: both
// Wt-layout experiments (R5/R6) regressed (+23/+30 us); the fp32 W gather
// is lane-coalesced and L2-hot. Do not touch without direct gemm counters.
// ---------------------------------------------------------------------------
__global__ __launch_bounds__(256) void gemm_kernel(
        const __half* __restrict__ x,
        const float* __restrict__ Wl, const float* __restrict__ Wr,
        const float* __restrict__ bl, const float* __restrict__ br,
        __half* __restrict__ xl, __half* __restrict__ xr, int N) {
    int w    = threadIdx.x >> 6;   // wave 0..3
    int lane = threadIdx.x & 63;
    int lo   = lane & 15;
    int hi   = lane >> 4;
    const float* W    = blockIdx.y ? Wr : Wl;
    const float* bias = blockIdx.y ? br : bl;
    __half*      out  = blockIdx.y ? xr : xl;
    int wbase = w * 64;
    int r0    = blockIdx.x * 64;

    half4v aw[4][4];
    float4 bv[4];
#pragma unroll
    for (int mt = 0; mt < 4; ++mt) {
        int c = wbase + mt * 16 + lo;
#pragma unroll
        for (int kt = 0; kt < 4; ++kt) {
            int k = kt * 16 + hi * 4;
            float f0 = W[(size_t)(k + 0) * 256 + c];
            float f1 = W[(size_t)(k + 1) * 256 + c];
            float f2 = W[(size_t)(k + 2) * 256 + c];
            float f3 = W[(size_t)(k + 3) * 256 + c];
            half2v p0 = __builtin_amdgcn_cvt_pkrtz(f0, f1);
            half2v p1 = __builtin_amdgcn_cvt_pkrtz(f2, f3);
            aw[mt][kt][0] = p0[0]; aw[mt][kt][1] = p0[1];
            aw[mt][kt][2] = p1[0]; aw[mt][kt][3] = p1[1];
        }
        bv[mt] = *(const float4*)(bias + wbase + mt * 16 + hi * 4);
    }

    half4v xv[4][4];
#pragma unroll
    for (int nt = 0; nt < 4; ++nt) {
        int row = min(r0 + nt * 16 + lo, N - 1);
        const __half* p = x + (size_t)row * 64 + hi * 4;
#pragma unroll
        for (int kt = 0; kt < 4; ++kt)
            xv[nt][kt] = *(const half4v*)(p + kt * 16);
    }

    f32x4 acc[4][4];
#pragma unroll
    for (int mt = 0; mt < 4; ++mt)
#pragma unroll
        for (int nt = 0; nt < 4; ++nt)
            acc[mt][nt] = (f32x4){0.f, 0.f, 0.f, 0.f};

#pragma unroll
    for (int kt = 0; kt < 4; ++kt)
#pragma unroll
        for (int mt = 0; mt < 4; ++mt)
#pragma unroll
            for (int nt = 0; nt < 4; ++nt)
                acc[mt][nt] = __builtin_amdgcn_mfma_f32_16x16x16f16(
                    aw[mt][kt], xv[nt][kt], acc[mt][nt], 0, 0, 0);

#pragma unroll
    for (int nt = 0; nt < 4; ++nt) {
        int row = r0 + nt * 16 + lo;
        if (row < N) {
#pragma unroll
            for (int mt = 0; mt < 4; ++mt) {
                f32x4 a = acc[mt][nt];
                half2v p0 = __builtin_amdgcn_cvt_pkrtz(a[0] + bv[mt].x, a[1] + bv[mt].y);
                half2v p1 = __builtin_amdgcn_cvt_pkrtz(a[2] + bv[mt].z, a[3] + bv[mt].w);
                union { half2v h[2]; uint2 u; } st;
                st.h[0] = p0; st.h[1] = p1;
                int c = wbase + mt * 16 + hi * 4;
                *(uint2*)(out + (size_t)row * 256 + c) = st.u;
            }
        }
    }
}

// ---------------------------------------------------------------------------
// CSR build (self loop at each segment head, +1 folded into scan).
// ---------------------------------------------------------------------------
__global__ void scan_block_kernel(const int* __restrict__ counts, int* __restrict__ excl,
                                  int* __restrict__ blockSums, int N) {
    __shared__ int lds[256];
    int b = blockIdx.x, t = threadIdx.x;
    int base = b * 1024 + t * 4;
    int v0 = (base + 0 < N) ? counts[base + 0] + 1 : 0;
    int v1 = (base + 1 < N) ? counts[base + 1] + 1 : 0;
    int v2 = (base + 2 < N) ? counts[base + 2] + 1 : 0;
    int v3 = (base + 3 < N) ? counts[base + 3] + 1 : 0;
    int s = v0 + v1 + v2 + v3;
    lds[t] = s;
    __syncthreads();
    for (int off = 1; off < 256; off <<= 1) {
        int add = (t >= off) ? lds[t - off] : 0;
        __syncthreads();
        lds[t] += add;
        __syncthreads();
    }
    int run = lds[t] - s;
    if (base + 0 < N) excl[base + 0] = run; run += v0;
    if (base + 1 < N) excl[base + 1] = run; run += v1;
    if (base + 2 < N) excl[base + 2] = run; run += v2;
    if (base + 3 < N) excl[base + 3] = run;
    if (t == 255) blockSums[b] = lds[255];
}

__global__ void finalize_kernel(int* __restrict__ csr_off, const int* __restrict__ blockSums,
                                int* __restrict__ cursor, int* __restrict__ csr_src,
                                int N, int total, int nb) {
    __shared__ int incl[64];
    __shared__ int excl[64];
    int t = threadIdx.x;
    if (t < 64) incl[t] = (t < nb) ? blockSums[t] : 0;
    __syncthreads();
    for (int off = 1; off < 64; off <<= 1) {
        int add = (t >= off && t < 64) ? incl[t - off] : 0;
        __syncthreads();
        if (t < 64) incl[t] += add;
        __syncthreads();
    }
    if (t < 64) excl[t] = t ? incl[t - 1] : 0;
    __syncthreads();

    int i = blockIdx.x * 256 + t;
    if (i < N) {
        int v = csr_off[i] + excl[i >> 10];
        csr_off[i] = v;
        csr_src[v] = i;    // self loop at segment head
        cursor[i]  = v + 1;
    }
    if (i == 0) csr_off[N] = total;
}

__global__ void scatter_kernel(const int* __restrict__ src, const int* __restrict__ dst,
                               int* __restrict__ cursor, int* __restrict__ csr_src, int E) {
    int e = blockIdx.x * 256 + threadIdx.x;
    if (e < E) {
        int pos = atomicAdd(&cursor[dst[e]], 1);
        csr_src[pos] = src[e];
    }
}

// ---------------------------------------------------------------------------
// GATv2 aggregation v8: one wave per dst node, TWO edges per gather
// instruction. Lanes split: hf=lane>>5 picks the edge sub-group, sl=lane&31
// covers 8 dims (16B) -> each uint4 row-load fetches two edges' 512B rows
// (halves VMEM instruction count; attacks the ~10K-gathers/us instr-rate
// wall evidenced by R0 fp32 @3.4TB/s vs fp16 @2.6TB/s). Head = sl>>3;
// logit reduce = 3 DPP steps (xor1, xor2, half-mirror within 8 lanes);
// halves merged via shfl_xor 32; head-mean via shfl_xor 8,16.
// Blocks of 8 edges; flat for m<=16, 2-buffer ping-pong beyond.
// ---------------------------------------------------------------------------
__global__ __launch_bounds__(256) void agg_kernel(
        const __half* __restrict__ xl, const __half* __restrict__ xr,
        const int* __restrict__ csr_off, const int* __restrict__ csr_src,
        const float* __restrict__ att,   // [4*64] this layer
        const float* __restrict__ gbias, // [64] this layer
        __half* __restrict__ xout, int N, int apply_gelu) {
    int wave = threadIdx.x >> 6;
    int lane = threadIdx.x & 63;
    int hf   = lane >> 5;      // edge sub-group (0: edges k..k+3, 1: k+4..k+7)
    int sl   = lane & 31;      // dim-slot: dims 8*sl .. 8*sl+7 (head = sl>>3)
    int n = __builtin_amdgcn_readfirstlane(blockIdx.x * 4 + wave);
    if (n >= N) return;

    union HU4 { uint4 u; half2v h[4]; };

    // att: 8 floats for this lane's dims, scaled by LOG2E, packed fp16
    float4 af0 = *(const float4*)(att + sl * 8);
    float4 af1 = *(const float4*)(att + sl * 8 + 4);
    half2v attp[4];
    attp[0] = __builtin_amdgcn_cvt_pkrtz(af0.x * LOG2E, af0.y * LOG2E);
    attp[1] = __builtin_amdgcn_cvt_pkrtz(af0.z * LOG2E, af0.w * LOG2E);
    attp[2] = __builtin_amdgcn_cvt_pkrtz(af1.x * LOG2E, af1.y * LOG2E);
    attp[3] = __builtin_amdgcn_cvt_pkrtz(af1.z * LOG2E, af1.w * LOG2E);

    HU4 xru; xru.u = *(const uint4*)(xr + (size_t)n * 256 + sl * 8);
    const half2v ns2 = {(__fp16)NEG_SLOPE, (__fp16)NEG_SLOPE};

    int beg  = csr_off[n];       // uniform -> s_load
    int end  = csr_off[n + 1];
    int m    = end - beg;        // includes self loop, >= 1
    int last = end - 1;

    const __half* __restrict__ xlp = xl + sl * 8;

    // lane's 4 edge indices for the 8-edge block starting at pos
    auto idx4h = [&](int pos) -> int4 {
        int p = pos + (hf << 2);
        if (p + 3 <= last) {
            int4 v; __builtin_memcpy(&v, csr_src + p, 16); return v;
        }
        int4 v;
        v.x = csr_src[min(p,     last)];
        v.y = csr_src[min(p + 1, last)];
        v.z = csr_src[min(p + 2, last)];
        v.w = csr_src[min(p + 3, last)];
        return v;
    };
    auto rows8 = [&](const int4& iv, uint4& r0, uint4& r1, uint4& r2, uint4& r3) {
        r0 = *(const uint4*)(xlp + (size_t)iv.x * 256);
        r1 = *(const uint4*)(xlp + (size_t)iv.y * 256);
        r2 = *(const uint4*)(xlp + (size_t)iv.z * 256);
        r3 = *(const uint4*)(xlp + (size_t)iv.w * 256);
    };
    // packed-fp16 logit partial over this lane's 8 dims (fp32 inside v_dot2)
    auto logit8 = [&](const HU4& e) -> float {
        float a = 0.f;
#pragma unroll
        for (int q = 0; q < 4; ++q) {
            half2v s = e.h[q] + xru.h[q];
            half2v t = __builtin_elementwise_max(s, s * ns2);
            a = FDOT2(t, attp[q], a);
        }
        return a;
    };

    float accd[8] = {0.f, 0.f, 0.f, 0.f, 0.f, 0.f, 0.f, 0.f};
    float denom = 0.f;

    auto compute8 = [&](const uint4& q0, const uint4& q1, const uint4& q2,
                        const uint4& q3, int kbase) {
        HU4 e0, e1, e2, e3;
        e0.u = q0; e1.u = q1; e2.u = q2; e3.u = q3;
        float p0 = logit8(e0), p1 = logit8(e1), p2 = logit8(e2), p3 = logit8(e3);
        // reduce over the 8 lanes of this head-group: xor1, xor2, half-mirror
        DPP_ADD(p0, 0xB1);  DPP_ADD(p1, 0xB1);  DPP_ADD(p2, 0xB1);  DPP_ADD(p3, 0xB1);
        DPP_ADD(p0, 0x4E);  DPP_ADD(p1, 0x4E);  DPP_ADD(p2, 0x4E);  DPP_ADD(p3, 0x4E);
        DPP_ADD(p0, 0x141); DPP_ADD(p1, 0x141); DPP_ADD(p2, 0x141); DPP_ADD(p3, 0x141);
        int base = kbase + (hf << 2);
        float w0 = (base     < m) ? EXP2(p0) : 0.f;
        float w1 = (base + 1 < m) ? EXP2(p1) : 0.f;
        float w2 = (base + 2 < m) ? EXP2(p2) : 0.f;
        float w3 = (base + 3 < m) ? EXP2(p3) : 0.f;
        denom += (w0 + w1) + (w2 + w3);
#pragma unroll
        for (int q = 0; q < 4; ++q) {
            accd[2 * q]     += w0 * (float)e0.h[q][0] + w1 * (float)e1.h[q][0]
                             + w2 * (float)e2.h[q][0] + w3 * (float)e3.h[q][0];
            accd[2 * q + 1] += w0 * (float)e0.h[q][1] + w1 * (float)e1.h[q][1]
                             + w2 * (float)e2.h[q][1] + w3 * (float)e3.h[q][1];
        }
    };

    uint4 a0, a1, a2, a3, b0, b1, b2, b3;
    if (m <= 8) {
        rows8(idx4h(beg), a0, a1, a2, a3);
        compute8(a0, a1, a2, a3, 0);
    } else if (m <= 16) {
        int4 i0 = idx4h(beg), i1 = idx4h(beg + 8);
        rows8(i0, a0, a1, a2, a3);
        rows8(i1, b0, b1, b2, b3);
        compute8(a0, a1, a2, a3, 0);
        compute8(b0, b1, b2, b3, 8);
    } else {                               // m > 16 (~3%): 2-buffer ping-pong
        rows8(idx4h(beg),     a0, a1, a2, a3);
        rows8(idx4h(beg + 8), b0, b1, b2, b3);
        int g = 0;
        while (true) {
            compute8(a0, a1, a2, a3, g);
            if (g + 8 >= m) break;
            if (g + 16 < m) rows8(idx4h(beg + g + 16), a0, a1, a2, a3);
            compute8(b0, b1, b2, b3, g + 8);
            if (g + 16 >= m) break;
            if (g + 24 < m) rows8(idx4h(beg + g + 24), b0, b1, b2, b3);
            g += 16;
        }
    }

    // merge the two edge sub-groups
    denom += __shfl_xor(denom, 32);
#pragma unroll
    for (int q = 0; q < 8; ++q) accd[q] += __shfl_xor(accd[q], 32);

    float inv = 1.f / denom;   // per-head denom (lane's head)
#pragma unroll
    for (int q = 0; q < 8; ++q) {
        float r = accd[q] * inv;
        r += __shfl_xor(r, 8);     // head-mean: heads at sl>>3
        r += __shfl_xor(r, 16);
        accd[q] = r;
    }

    if (lane < 8) {
        float4 bv0 = *(const float4*)(gbias + lane * 8);
        float4 bv1 = *(const float4*)(gbias + lane * 8 + 4);
        float o[8];
        o[0] = 0.25f * accd[0] + bv0.x;  o[1] = 0.25f * accd[1] + bv0.y;
        o[2] = 0.25f * accd[2] + bv0.z;  o[3] = 0.25f * accd[3] + bv0.w;
        o[4] = 0.25f * accd[4] + bv1.x;  o[5] = 0.25f * accd[5] + bv1.y;
        o[6] = 0.25f * accd[6] + bv1.z;  o[7] = 0.25f * accd[7] + bv1.w;
        if (apply_gelu) {
            const float kk = 0.70710678118654752440f;
#pragma unroll
            for (int q = 0; q < 8; ++q)
                o[q] = 0.5f * o[q] * (1.f + erff(o[q] * kk));
        }
        uint4 st = make_uint4(f2h2(o[0], o[1]), f2h2(o[2], o[3]),
                              f2h2(o[4], o[5]), f2h2(o[6], o[7]));
        *(uint4*)(xout + (size_t)n * 64 + lane * 8) = st;
    }
}

// ---------------------------------------------------------------------------
// Global mean pool (batch sorted) + classifier. Block per graph, 256 threads.
// ---------------------------------------------------------------------------
__global__ __launch_bounds__(256) void pool_kernel(
        const __half* __restrict__ x, const int* __restrict__ batch,
        const float* __restrict__ Wc, const float* __restrict__ bc,
        float* __restrict__ out, int N, int G) {
    __shared__ float part[4][64];
    __shared__ float pooled[64];
    int g = blockIdx.x, t = threadIdx.x;
    int sub = t >> 6, lane = t & 63;
    int lo = 0, hi = N;
    while (lo < hi) { int mid = (lo + hi) >> 1; if (batch[mid] < g) lo = mid + 1; else hi = mid; }
    int beg = lo;
    hi = N;
    while (lo < hi) { int mid = (lo + hi) >> 1; if (batch[mid] < g + 1) lo = mid + 1; else hi = mid; }
    int end = lo;

    float acc = 0.f;
    for (int n = beg + sub; n < end; n += 4) acc += __half2float(x[(size_t)n * 64 + lane]);
    part[sub][lane] = acc;
    __syncthreads();
    if (t < 64) {
        float s = (part[0][t] + part[1][t]) + (part[2][t] + part[3][t]);
        int cnt = end - beg;
        pooled[t] = (cnt > 0) ? s / (float)cnt : 0.f;
    }
    __syncthreads();
    if (t < 10) {
        float o = bc[t];
        for (int d = 0; d < 64; ++d) o += pooled[d] * Wc[d * 10 + t];
        out[(size_t)g * 10 + t] = o;
    }
}

// ---------------------------------------------------------------------------
extern "C" void kernel_launch(void* const* d_in, const int* in_sizes, int n_in,
                              void* d_out, int out_size, void* d_ws, size_t ws_size,
                              hipStream_t stream) {
    const int*   feat  = (const int*)d_in[0];
    const int*   edges = (const int*)d_in[1];
    const int*   batch = (const int*)d_in[2];
    const float* emb   = (const float*)d_in[3];
    const float* Wl    = (const float*)d_in[4];
    const float* bl    = (const float*)d_in[5];
    const float* Wr    = (const float*)d_in[6];
    const float* br    = (const float*)d_in[7];
    const float* att   = (const float*)d_in[8];
    const float* gb    = (const float*)d_in[9];
    const float* Wc    = (const float*)d_in[10];
    const float* bc    = (const float*)d_in[11];
    float* out = (float*)d_out;

    const int N = in_sizes[2];
    const int E = in_sizes[1] / 2;
    const int G = out_size / 10;

    char* ws = (char*)d_ws;
    size_t off = 0;
    auto alloc = [&](size_t bytes) -> char* {
        char* p = ws + off;
        off = (off + bytes + 255) & ~(size_t)255;
        return p;
    };
    __half* x         = (__half*)alloc((size_t)N * 64 * 2);
    __half* xl        = (__half*)alloc((size_t)N * 256 * 2);
    __half* xr        = (__half*)alloc((size_t)N * 256 * 2);
    int*    counts    = (int*)alloc((size_t)N * 4);
    int*    csr_off   = (int*)alloc((size_t)(N + 8) * 4);
    int*    cursor    = (int*)alloc((size_t)N * 4);
    int*    csr_src   = (int*)alloc((size_t)(E + N + 64) * 4);
    int*    blockSums = (int*)alloc(256 * 4);

    const int* srcv = edges;
    const int* dstv = edges + E;

    // 1) zero counts, fused embed + histogram
    hipMemsetAsync(counts, 0, (size_t)N * 4, stream);
    hipLaunchKernelGGL(embed_kernel, dim3((N + 3) / 4), dim3(256), 0, stream,
                       feat, emb, dstv, counts, x, N, E);

    // 2) CSR by destination, self-loop at each segment head (+1 in scan)
    int nb = (N + 1023) / 1024;
    hipLaunchKernelGGL(scan_block_kernel, dim3(nb), dim3(256), 0, stream, counts, csr_off, blockSums, N);
    hipLaunchKernelGGL(finalize_kernel, dim3((N + 255) / 256), dim3(256), 0, stream,
                       csr_off, blockSums, cursor, csr_src, N, E + N, nb);
    hipLaunchKernelGGL(scatter_kernel, dim3((E + 255) / 256), dim3(256), 0, stream, srcv, dstv, cursor, csr_src, E);

    // 3) GATv2 layers
    int nchunks = (N + 63) / 64;
    for (int l = 0; l < 3; ++l) {
        hipLaunchKernelGGL(gemm_kernel, dim3(nchunks, 2), dim3(256), 0, stream,
                           x, Wl + (size_t)l * 64 * 256, Wr + (size_t)l * 64 * 256,
                           bl + l * 256, br + l * 256, xl, xr, N);
        hipLaunchKernelGGL(agg_kernel, dim3((N + 3) / 4), dim3(256), 0, stream,
                           xl, xr, csr_off, csr_src, att + l * 256, gb + l * 64,
                           x, N, (l < 2) ? 1 : 0);
    }

    // 4) pool + classify
    hipLaunchKernelGGL(pool_kernel, dim3(G), dim3(256), 0, stream, x, batch, Wc, bc, out, N, G);
}

// Round 10
// 337.853 us; speedup vs baseline: 1.0967x; 1.0967x over previous
//
#include <hip/hip_runtime.h>
#include <hip/hip_fp16.h>
#include <math.h>

#define NEG_SLOPE 0.2f
#define LOG2E 1.44269504088896340736f

#if __has_builtin(__builtin_amdgcn_exp2f)
#define EXP2(x) __builtin_amdgcn_exp2f(x)
#else
#define EXP2(x) exp2f(x)
#endif

// in-wave butterfly add via DPP (plain VALU, no DS pipe): validated R5/R6.
#define DPP_ADD(p, ctrl) \
    p += __int_as_float(__builtin_amdgcn_update_dpp(0, __float_as_int(p), ctrl, 0xf, 0xf, true))

typedef __fp16 half4v __attribute__((ext_vector_type(4)));
typedef __fp16 half2v __attribute__((ext_vector_type(2)));
typedef float  f32x4  __attribute__((ext_vector_type(4)));

// fp16 pack/unpack helpers (storage-only fp16; all math fp32)
__device__ __forceinline__ unsigned f2h2(float x, float y) {
    union { unsigned u; __half2 h; } r;
    r.h = __floats2half2_rn(x, y);
    return r.u;
}

// dot2: fp16 pair x fp16 pair + f32 -> f32 (v_dot2_f32_f16)
#if __has_builtin(__builtin_amdgcn_fdot2)
#define FDOT2(a, b, c) __builtin_amdgcn_fdot2((a), (b), (c), false)
#else
__device__ __forceinline__ float FDOT2(half2v a, half2v b, float c) {
    return c + (float)a[0] * (float)b[0] + (float)a[1] * (float)b[1];
}
#endif

// ---------------------------------------------------------------------------
// AtomEncoder + edge histogram (fused). x stored fp16.
// ---------------------------------------------------------------------------
__global__ __launch_bounds__(256) void embed_kernel(
        const int* __restrict__ feat, const float* __restrict__ emb,
        const int* __restrict__ dstE, int* __restrict__ counts,
        __half* __restrict__ x, int N, int E) {
    int gid = blockIdx.x * 256 + threadIdx.x;
    if (gid < E) atomicAdd(&counts[dstE[gid]], 1);

    const int offs[9] = {0, 119, 124, 136, 148, 158, 164, 170, 172};
    int sub  = threadIdx.x >> 6;
    int lane = threadIdx.x & 63;
    int n = __builtin_amdgcn_readfirstlane(blockIdx.x * 4 + sub);
    if (n >= N) return;
    float s = 0.f;
#pragma unroll
    for (int j = 0; j < 9; ++j) {
        int idx = feat[n * 9 + j] + offs[j];
        s += emb[idx * 64 + lane];
    }
    x[(size_t)n * 64 + lane] = __float2half(s);
}

// ---------------------------------------------------------------------------
// Dual GEMM (MFMA) v6: R4 compute (FROZEN: W gather lane-coalesced, L2-hot;
// Wt experiments regressed) + NEW LDS-staged epilogue. Old epilogue stored
// uint2/lane at 512B lane stride -> wave store = 16 scattered 32B chunks
// (~1/4 efficiency on 51.2MB/dispatch = suspected ~40us wall). Now: stage
// the 64x256 fp16 tile in LDS (XOR-swizzled, ds_write <=2-way), barrier,
// store contiguous 1KB/wave-instruction (tile is 32KB contiguous in out).
// Layouts (m89-verified family): A-frag lane l: row=l&15, k=(l>>4)*4+j;
// B-frag: col=l&15, same k; D: col=l&15, row=(l>>4)*4+reg.
// ---------------------------------------------------------------------------
__global__ __launch_bounds__(256) void gemm_kernel(
        const __half* __restrict__ x,
        const float* __restrict__ Wl, const float* __restrict__ Wr,
        const float* __restrict__ bl, const float* __restrict__ br,
        __half* __restrict__ xl, __half* __restrict__ xr, int N) {
    __shared__ __align__(16) unsigned char lds[32768];   // 64 rows x 512 B
    int t    = threadIdx.x;
    int w    = t >> 6;             // wave 0..3
    int lane = t & 63;
    int lo   = lane & 15;
    int hi   = lane >> 4;
    const float* W    = blockIdx.y ? Wr : Wl;
    const float* bias = blockIdx.y ? br : bl;
    __half*      out  = blockIdx.y ? xr : xl;
    int wbase = w * 64;
    int r0    = blockIdx.x * 64;

    half4v aw[4][4];
    float4 bv[4];
#pragma unroll
    for (int mt = 0; mt < 4; ++mt) {
        int c = wbase + mt * 16 + lo;
#pragma unroll
        for (int kt = 0; kt < 4; ++kt) {
            int k = kt * 16 + hi * 4;
            float f0 = W[(size_t)(k + 0) * 256 + c];
            float f1 = W[(size_t)(k + 1) * 256 + c];
            float f2 = W[(size_t)(k + 2) * 256 + c];
            float f3 = W[(size_t)(k + 3) * 256 + c];
            half2v p0 = __builtin_amdgcn_cvt_pkrtz(f0, f1);
            half2v p1 = __builtin_amdgcn_cvt_pkrtz(f2, f3);
            aw[mt][kt][0] = p0[0]; aw[mt][kt][1] = p0[1];
            aw[mt][kt][2] = p1[0]; aw[mt][kt][3] = p1[1];
        }
        bv[mt] = *(const float4*)(bias + wbase + mt * 16 + hi * 4);
    }

    half4v xv[4][4];
#pragma unroll
    for (int nt = 0; nt < 4; ++nt) {
        int row = min(r0 + nt * 16 + lo, N - 1);
        const __half* p = x + (size_t)row * 64 + hi * 4;
#pragma unroll
        for (int kt = 0; kt < 4; ++kt)
            xv[nt][kt] = *(const half4v*)(p + kt * 16);
    }

    f32x4 acc[4][4];
#pragma unroll
    for (int mt = 0; mt < 4; ++mt)
#pragma unroll
        for (int nt = 0; nt < 4; ++nt)
            acc[mt][nt] = (f32x4){0.f, 0.f, 0.f, 0.f};

#pragma unroll
    for (int kt = 0; kt < 4; ++kt)
#pragma unroll
        for (int mt = 0; mt < 4; ++mt)
#pragma unroll
            for (int nt = 0; nt < 4; ++nt)
                acc[mt][nt] = __builtin_amdgcn_mfma_f32_16x16x16f16(
                    aw[mt][kt], xv[nt][kt], acc[mt][nt], 0, 0, 0);

    // Epilogue 1: bias + pack + LDS write (swizzled; <=2-way bank aliasing)
#pragma unroll
    for (int nt = 0; nt < 4; ++nt) {
        int row = nt * 16 + lo;                 // 0..63 within tile
#pragma unroll
        for (int mt = 0; mt < 4; ++mt) {
            f32x4 a = acc[mt][nt];
            half2v p0 = __builtin_amdgcn_cvt_pkrtz(a[0] + bv[mt].x, a[1] + bv[mt].y);
            half2v p1 = __builtin_amdgcn_cvt_pkrtz(a[2] + bv[mt].z, a[3] + bv[mt].w);
            union { half2v h[2]; uint2 u; } st;
            st.h[0] = p0; st.h[1] = p1;
            int byte = row * 512 + (wbase + mt * 16 + hi * 4) * 2;
            byte ^= (row & 7) << 4;             // XOR swizzle, bijective/row
            *(uint2*)(lds + byte) = st.u;
        }
    }
    __syncthreads();

    // Epilogue 2: coalesced read-back + 1KB/wave-instr contiguous stores
#pragma unroll
    for (int it = 0; it < 8; ++it) {
        int row = (t >> 5) + it * 8;            // 0..63
        int cb  = (t & 31) * 16;                // byte within row
        int byte = row * 512 + cb;
        byte ^= (row & 7) << 4;
        uint4 v = *(const uint4*)(lds + byte);
        if (r0 + row < N)
            *(uint4*)((unsigned char*)out + (size_t)(r0 + row) * 512 + cb) = v;
    }
}

// ---------------------------------------------------------------------------
// CSR build (self loop at each segment head, +1 folded into scan).
// ---------------------------------------------------------------------------
__global__ void scan_block_kernel(const int* __restrict__ counts, int* __restrict__ excl,
                                  int* __restrict__ blockSums, int N) {
    __shared__ int lds[256];
    int b = blockIdx.x, t = threadIdx.x;
    int base = b * 1024 + t * 4;
    int v0 = (base + 0 < N) ? counts[base + 0] + 1 : 0;
    int v1 = (base + 1 < N) ? counts[base + 1] + 1 : 0;
    int v2 = (base + 2 < N) ? counts[base + 2] + 1 : 0;
    int v3 = (base + 3 < N) ? counts[base + 3] + 1 : 0;
    int s = v0 + v1 + v2 + v3;
    lds[t] = s;
    __syncthreads();
    for (int off = 1; off < 256; off <<= 1) {
        int add = (t >= off) ? lds[t - off] : 0;
        __syncthreads();
        lds[t] += add;
        __syncthreads();
    }
    int run = lds[t] - s;
    if (base + 0 < N) excl[base + 0] = run; run += v0;
    if (base + 1 < N) excl[base + 1] = run; run += v1;
    if (base + 2 < N) excl[base + 2] = run; run += v2;
    if (base + 3 < N) excl[base + 3] = run;
    if (t == 255) blockSums[b] = lds[255];
}

__global__ void finalize_kernel(int* __restrict__ csr_off, const int* __restrict__ blockSums,
                                int* __restrict__ cursor, int* __restrict__ csr_src,
                                int N, int total, int nb) {
    __shared__ int incl[64];
    __shared__ int excl[64];
    int t = threadIdx.x;
    if (t < 64) incl[t] = (t < nb) ? blockSums[t] : 0;
    __syncthreads();
    for (int off = 1; off < 64; off <<= 1) {
        int add = (t >= off && t < 64) ? incl[t - off] : 0;
        __syncthreads();
        if (t < 64) incl[t] += add;
        __syncthreads();
    }
    if (t < 64) excl[t] = t ? incl[t - 1] : 0;
    __syncthreads();

    int i = blockIdx.x * 256 + t;
    if (i < N) {
        int v = csr_off[i] + excl[i >> 10];
        csr_off[i] = v;
        csr_src[v] = i;    // self loop at segment head
        cursor[i]  = v + 1;
    }
    if (i == 0) csr_off[N] = total;
}

__global__ void scatter_kernel(const int* __restrict__ src, const int* __restrict__ dst,
                               int* __restrict__ cursor, int* __restrict__ csr_src, int E) {
    int e = blockIdx.x * 256 + threadIdx.x;
    if (e < E) {
        int pos = atomicAdd(&cursor[dst[e]], 1);
        csr_src[pos] = src[e];
    }
}

// ---------------------------------------------------------------------------
// GATv2 aggregation v7 (R8 exact -- best measured; v8 two-edge remap
// regressed +4us, REVERTED). One wave per dst node. Packed-fp16 logit path.
// Degree-adaptive flat paths m<=4/8/12/16, rotating pipeline for m>16.
// ---------------------------------------------------------------------------
__global__ __launch_bounds__(256) void agg_kernel(
        const __half* __restrict__ xl, const __half* __restrict__ xr,
        const int* __restrict__ csr_off, const int* __restrict__ csr_src,
        const float* __restrict__ att,   // [4*64] this layer
        const float* __restrict__ gbias, // [64] this layer
        __half* __restrict__ xout, int N, int apply_gelu) {
    int wave = threadIdx.x >> 6;
    int lane = threadIdx.x & 63;
    int n = __builtin_amdgcn_readfirstlane(blockIdx.x * 4 + wave);
    if (n >= N) return;

    union HU { uint2 u; half2v h[2]; };

    float4 attf = ((const float4*)att)[lane];
    half2v att_lo = __builtin_amdgcn_cvt_pkrtz(attf.x * LOG2E, attf.y * LOG2E);
    half2v att_hi = __builtin_amdgcn_cvt_pkrtz(attf.z * LOG2E, attf.w * LOG2E);

    HU xru; xru.u = *(const uint2*)(xr + (size_t)n * 256 + lane * 4);
    half2v xr_lo = xru.h[0], xr_hi = xru.h[1];
    const half2v ns2 = {(__fp16)NEG_SLOPE, (__fp16)NEG_SLOPE};

    int beg  = csr_off[n];       // uniform -> s_load
    int end  = csr_off[n + 1];
    int m    = end - beg;        // includes self loop, >= 1
    int last = end - 1;

    const __half* __restrict__ xlp = xl + lane * 4;

    auto idx4 = [&](int pos) -> int4 {
        if (pos + 3 <= last) {            // uniform branch; aligned-enough
            int4 v;
            __builtin_memcpy(&v, csr_src + pos, 16);
            return v;
        }
        int4 v;
        v.x = csr_src[min(pos,     last)];
        v.y = csr_src[min(pos + 1, last)];
        v.z = csr_src[min(pos + 2, last)];
        v.w = csr_src[min(pos + 3, last)];
        return v;
    };
    auto rows4 = [&](const int4& iv, uint2& r0, uint2& r1, uint2& r2, uint2& r3) {
        r0 = *(const uint2*)(xlp + (size_t)iv.x * 256);
        r1 = *(const uint2*)(xlp + (size_t)iv.y * 256);
        r2 = *(const uint2*)(xlp + (size_t)iv.z * 256);
        r3 = *(const uint2*)(xlp + (size_t)iv.w * 256);
    };
    // packed-fp16 logit: s=xl+xr, leaky, att-dot (fp32 inside v_dot2)
    auto logit = [&](half2v lo, half2v hi) -> float {
        half2v s0 = lo + xr_lo;
        half2v s1 = hi + xr_hi;
        half2v t0 = __builtin_elementwise_max(s0, s0 * ns2);
        half2v t1 = __builtin_elementwise_max(s1, s1 * ns2);
        return FDOT2(t1, att_hi, FDOT2(t0, att_lo, 0.f));
    };

    float ax = 0.f, ay = 0.f, az = 0.f, aw = 0.f, denom = 0.f;

    auto compute4 = [&](const uint2& q0, const uint2& q1, const uint2& q2,
                        const uint2& q3, int kbase) {
        HU e0, e1, e2, e3;
        e0.u = q0; e1.u = q1; e2.u = q2; e3.u = q3;
        float p0 = logit(e0.h[0], e0.h[1]);
        float p1 = logit(e1.h[0], e1.h[1]);
        float p2 = logit(e2.h[0], e2.h[1]);
        float p3 = logit(e3.h[0], e3.h[1]);
        DPP_ADD(p0, 0xB1);  DPP_ADD(p1, 0xB1);  DPP_ADD(p2, 0xB1);  DPP_ADD(p3, 0xB1);
        DPP_ADD(p0, 0x4E);  DPP_ADD(p1, 0x4E);  DPP_ADD(p2, 0x4E);  DPP_ADD(p3, 0x4E);
        DPP_ADD(p0, 0x141); DPP_ADD(p1, 0x141); DPP_ADD(p2, 0x141); DPP_ADD(p3, 0x141);
        DPP_ADD(p0, 0x140); DPP_ADD(p1, 0x140); DPP_ADD(p2, 0x140); DPP_ADD(p3, 0x140);
        float w0 = EXP2(p0);                            // slot 0 always valid
        float w1 = (kbase + 1 < m) ? EXP2(p1) : 0.f;    // branchless tail
        float w2 = (kbase + 2 < m) ? EXP2(p2) : 0.f;
        float w3 = (kbase + 3 < m) ? EXP2(p3) : 0.f;
        denom += (w0 + w1) + (w2 + w3);
        // fp32 accumulate; (float)__fp16 * f32 + f32 folds to v_fma_mix_f32
        ax += w0 * (float)e0.h[0][0] + w1 * (float)e1.h[0][0]
            + w2 * (float)e2.h[0][0] + w3 * (float)e3.h[0][0];
        ay += w0 * (float)e0.h[0][1] + w1 * (float)e1.h[0][1]
            + w2 * (float)e2.h[0][1] + w3 * (float)e3.h[0][1];
        az += w0 * (float)e0.h[1][0] + w1 * (float)e1.h[1][0]
            + w2 * (float)e2.h[1][0] + w3 * (float)e3.h[1][0];
        aw += w0 * (float)e0.h[1][1] + w1 * (float)e1.h[1][1]
            + w2 * (float)e2.h[1][1] + w3 * (float)e3.h[1][1];
    };

    uint2 a0, a1, a2, a3, b0, b1, b2, b3, c0, c1, c2, c3;
    if (m <= 8) {
        rows4(idx4(beg), a0, a1, a2, a3);
        if (m <= 4) {                      // 1 block
            compute4(a0, a1, a2, a3, 0);
        } else {                           // 2 blocks
            rows4(idx4(beg + 4), b0, b1, b2, b3);
            compute4(a0, a1, a2, a3, 0);
            compute4(b0, b1, b2, b3, 4);
        }
    } else if (m <= 16) {
        // flat: issue all indices, then all rows, then compute (no waste)
        int4 i0 = idx4(beg), i1 = idx4(beg + 4), i2 = idx4(beg + 8);
        rows4(i0, a0, a1, a2, a3);
        rows4(i1, b0, b1, b2, b3);
        rows4(i2, c0, c1, c2, c3);
        if (m <= 12) {                     // 3 blocks
            compute4(a0, a1, a2, a3, 0);
            compute4(b0, b1, b2, b3, 4);
            compute4(c0, c1, c2, c3, 8);
        } else {                           // 4 blocks
            uint2 d0, d1, d2, d3;
            rows4(idx4(beg + 12), d0, d1, d2, d3);
            compute4(a0, a1, a2, a3, 0);
            compute4(b0, b1, b2, b3, 4);
            compute4(c0, c1, c2, c3, 8);
            compute4(d0, d1, d2, d3, 12);
        }
    } else {                               // m > 16 (~0.5%): rotating pipeline
        rows4(idx4(beg),     a0, a1, a2, a3);
        rows4(idx4(beg + 4), b0, b1, b2, b3);
        rows4(idx4(beg + 8), c0, c1, c2, c3);
        int4 ja = idx4(beg + 12);
        int4 jb = idx4(beg + 16);
        int4 jc = idx4(beg + 20);
        int g = 0;
        while (true) {
            compute4(a0, a1, a2, a3, g);
            if (g + 4 >= m) break;
            rows4(ja, a0, a1, a2, a3);  ja = idx4(beg + g + 24);

            compute4(b0, b1, b2, b3, g + 4);
            if (g + 8 >= m) break;
            rows4(jb, b0, b1, b2, b3);  jb = idx4(beg + g + 28);

            compute4(c0, c1, c2, c3, g + 8);
            if (g + 12 >= m) break;
            rows4(jc, c0, c1, c2, c3);  jc = idx4(beg + g + 32);

            g += 12;
        }
    }

    float inv = 1.f / denom;
    float rx = ax * inv, ry = ay * inv, rz = az * inv, rw = aw * inv;
    // head mean: lanes j, j^16, j^32, j^48 share feature d
    rx += __shfl_xor(rx, 16); rx += __shfl_xor(rx, 32);
    ry += __shfl_xor(ry, 16); ry += __shfl_xor(ry, 32);
    rz += __shfl_xor(rz, 16); rz += __shfl_xor(rz, 32);
    rw += __shfl_xor(rw, 16); rw += __shfl_xor(rw, 32);

    if (lane < 16) {
        int d0 = lane * 4;
        float4 bvv = *(const float4*)(gbias + d0);
        float ox = 0.25f * rx + bvv.x;
        float oy = 0.25f * ry + bvv.y;
        float oz = 0.25f * rz + bvv.z;
        float ow = 0.25f * rw + bvv.w;
        if (apply_gelu) {
            const float kk = 0.70710678118654752440f;
            ox = 0.5f * ox * (1.f + erff(ox * kk));
            oy = 0.5f * oy * (1.f + erff(oy * kk));
            oz = 0.5f * oz * (1.f + erff(oz * kk));
            ow = 0.5f * ow * (1.f + erff(ow * kk));
        }
        uint2 st = make_uint2(f2h2(ox, oy), f2h2(oz, ow));
        *(uint2*)(xout + (size_t)n * 64 + d0) = st;
    }
}

// ---------------------------------------------------------------------------
// Global mean pool (batch sorted) + classifier. Block per graph, 256 threads.
// ---------------------------------------------------------------------------
__global__ __launch_bounds__(256) void pool_kernel(
        const __half* __restrict__ x, const int* __restrict__ batch,
        const float* __restrict__ Wc, const float* __restrict__ bc,
        float* __restrict__ out, int N, int G) {
    __shared__ float part[4][64];
    __shared__ float pooled[64];
    int g = blockIdx.x, t = threadIdx.x;
    int sub = t >> 6, lane = t & 63;
    int lo = 0, hi = N;
    while (lo < hi) { int mid = (lo + hi) >> 1; if (batch[mid] < g) lo = mid + 1; else hi = mid; }
    int beg = lo;
    hi = N;
    while (lo < hi) { int mid = (lo + hi) >> 1; if (batch[mid] < g + 1) lo = mid + 1; else hi = mid; }
    int end = lo;

    float acc = 0.f;
    for (int n = beg + sub; n < end; n += 4) acc += __half2float(x[(size_t)n * 64 + lane]);
    part[sub][lane] = acc;
    __syncthreads();
    if (t < 64) {
        float s = (part[0][t] + part[1][t]) + (part[2][t] + part[3][t]);
        int cnt = end - beg;
        pooled[t] = (cnt > 0) ? s / (float)cnt : 0.f;
    }
    __syncthreads();
    if (t < 10) {
        float o = bc[t];
        for (int d = 0; d < 64; ++d) o += pooled[d] * Wc[d * 10 + t];
        out[(size_t)g * 10 + t] = o;
    }
}

// ---------------------------------------------------------------------------
extern "C" void kernel_launch(void* const* d_in, const int* in_sizes, int n_in,
                              void* d_out, int out_size, void* d_ws, size_t ws_size,
                              hipStream_t stream) {
    const int*   feat  = (const int*)d_in[0];
    const int*   edges = (const int*)d_in[1];
    const int*   batch = (const int*)d_in[2];
    const float* emb   = (const float*)d_in[3];
    const float* Wl    = (const float*)d_in[4];
    const float* bl    = (const float*)d_in[5];
    const float* Wr    = (const float*)d_in[6];
    const float* br    = (const float*)d_in[7];
    const float* att   = (const float*)d_in[8];
    const float* gb    = (const float*)d_in[9];
    const float* Wc    = (const float*)d_in[10];
    const float* bc    = (const float*)d_in[11];
    float* out = (float*)d_out;

    const int N = in_sizes[2];
    const int E = in_sizes[1] / 2;
    const int G = out_size / 10;

    char* ws = (char*)d_ws;
    size_t off = 0;
    auto alloc = [&](size_t bytes) -> char* {
        char* p = ws + off;
        off = (off + bytes + 255) & ~(size_t)255;
        return p;
    };
    __half* x         = (__half*)alloc((size_t)N * 64 * 2);
    __half* xl        = (__half*)alloc((size_t)N * 256 * 2);
    __half* xr        = (__half*)alloc((size_t)N * 256 * 2);
    int*    counts    = (int*)alloc((size_t)N * 4);
    int*    csr_off   = (int*)alloc((size_t)(N + 8) * 4);
    int*    cursor    = (int*)alloc((size_t)N * 4);
    int*    csr_src   = (int*)alloc((size_t)(E + N + 64) * 4);
    int*    blockSums = (int*)alloc(256 * 4);

    const int* srcv = edges;
    const int* dstv = edges + E;

    // 1) zero counts, fused embed + histogram
    hipMemsetAsync(counts, 0, (size_t)N * 4, stream);
    hipLaunchKernelGGL(embed_kernel, dim3((N + 3) / 4), dim3(256), 0, stream,
                       feat, emb, dstv, counts, x, N, E);

    // 2) CSR by destination, self-loop at each segment head (+1 in scan)
    int nb = (N + 1023) / 1024;
    hipLaunchKernelGGL(scan_block_kernel, dim3(nb), dim3(256), 0, stream, counts, csr_off, blockSums, N);
    hipLaunchKernelGGL(finalize_kernel, dim3((N + 255) / 256), dim3(256), 0, stream,
                       csr_off, blockSums, cursor, csr_src, N, E + N, nb);
    hipLaunchKernelGGL(scatter_kernel, dim3((E + 255) / 256), dim3(256), 0, stream, srcv, dstv, cursor, csr_src, E);

    // 3) GATv2 layers
    int nchunks = (N + 63) / 64;
    for (int l = 0; l < 3; ++l) {
        hipLaunchKernelGGL(gemm_kernel, dim3(nchunks, 2), dim3(256), 0, stream,
                           x, Wl + (size_t)l * 64 * 256, Wr + (size_t)l * 64 * 256,
                           bl + l * 256, br + l * 256, xl, xr, N);
        hipLaunchKernelGGL(agg_kernel, dim3((N + 3) / 4), dim3(256), 0, stream,
                           xl, xr, csr_off, csr_src, att + l * 256, gb + l * 64,
                           x, N, (l < 2) ? 1 : 0);
    }

    // 4) pool + classify
    hipLaunchKernelGGL(pool_kernel, dim3(G), dim3(256), 0, stream, x, batch, Wc, bc, out, N, G);
}

// Round 12
// 337.704 us; speedup vs baseline: 1.0971x; 1.0004x over previous
//
#include <hip/hip_runtime.h>
#include <hip/hip_fp16.h>
#include <math.h>

#define NEG_SLOPE 0.2f
#define LOG2E 1.44269504088896340736f

#if __has_builtin(__builtin_amdgcn_exp2f)
#define EXP2(x) __builtin_amdgcn_exp2f(x)
#else
#define EXP2(x) exp2f(x)
#endif

// in-wave butterfly add via DPP (plain VALU, no DS pipe): validated R5/R6.
#define DPP_ADD(p, ctrl) \
    p += __int_as_float(__builtin_amdgcn_update_dpp(0, __float_as_int(p), ctrl, 0xf, 0xf, true))

typedef __fp16 half4v __attribute__((ext_vector_type(4)));
typedef __fp16 half2v __attribute__((ext_vector_type(2)));
typedef float  f32x4  __attribute__((ext_vector_type(4)));

// fp16 pack/unpack helpers (storage-only fp16; all math fp32)
__device__ __forceinline__ unsigned f2h2(float x, float y) {
    union { unsigned u; __half2 h; } r;
    r.h = __floats2half2_rn(x, y);
    return r.u;
}

// dot2: fp16 pair x fp16 pair + f32 -> f32 (v_dot2_f32_f16)
#if __has_builtin(__builtin_amdgcn_fdot2)
#define FDOT2(a, b, c) __builtin_amdgcn_fdot2((a), (b), (c), false)
#else
__device__ __forceinline__ float FDOT2(half2v a, half2v b, float c) {
    return c + (float)a[0] * (float)b[0] + (float)a[1] * (float)b[1];
}
#endif

// ---------------------------------------------------------------------------
// AtomEncoder + edge histogram (fused). x stored fp16.
// ---------------------------------------------------------------------------
__global__ __launch_bounds__(256) void embed_kernel(
        const int* __restrict__ feat, const float* __restrict__ emb,
        const int* __restrict__ dstE, int* __restrict__ counts,
        __half* __restrict__ x, int N, int E) {
    int gid = blockIdx.x * 256 + threadIdx.x;
    if (gid < E) atomicAdd(&counts[dstE[gid]], 1);

    const int offs[9] = {0, 119, 124, 136, 148, 158, 164, 170, 172};
    int sub  = threadIdx.x >> 6;
    int lane = threadIdx.x & 63;
    int n = __builtin_amdgcn_readfirstlane(blockIdx.x * 4 + sub);
    if (n >= N) return;
    float s = 0.f;
#pragma unroll
    for (int j = 0; j < 9; ++j) {
        int idx = feat[n * 9 + j] + offs[j];
        s += emb[idx * 64 + lane];
    }
    x[(size_t)n * 64 + lane] = __float2half(s);
}

// ---------------------------------------------------------------------------
// Dual GEMM (MFMA) v6: R4 compute (FROZEN: W gather lane-coalesced, L2-hot;
// Wt experiments regressed) + LDS-staged coalesced epilogue (R10 validated,
// -21.6us: old per-lane uint2 stores at 512B stride were a scattered-store
// wall; staging the 64x256 tile in LDS and storing contiguous 1KB/wave
// fixed it). fp8 xl variant FAILED absmax (R11: 2e-4 > 7e-6 threshold) --
// fp16 storage is the precision floor. Layouts (m89-verified family):
// A-frag lane l: row=l&15, k=(l>>4)*4+j; B-frag: col=l&15, same k;
// D: col=l&15, row=(l>>4)*4+reg.
// ---------------------------------------------------------------------------
__global__ __launch_bounds__(256) void gemm_kernel(
        const __half* __restrict__ x,
        const float* __restrict__ Wl, const float* __restrict__ Wr,
        const float* __restrict__ bl, const float* __restrict__ br,
        __half* __restrict__ xl, __half* __restrict__ xr, int N) {
    __shared__ __align__(16) unsigned char lds[32768];   // 64 rows x 512 B
    int t    = threadIdx.x;
    int w    = t >> 6;             // wave 0..3
    int lane = t & 63;
    int lo   = lane & 15;
    int hi   = lane >> 4;
    const float* W    = blockIdx.y ? Wr : Wl;
    const float* bias = blockIdx.y ? br : bl;
    __half*      out  = blockIdx.y ? xr : xl;
    int wbase = w * 64;
    int r0    = blockIdx.x * 64;

    half4v aw[4][4];
    float4 bv[4];
#pragma unroll
    for (int mt = 0; mt < 4; ++mt) {
        int c = wbase + mt * 16 + lo;
#pragma unroll
        for (int kt = 0; kt < 4; ++kt) {
            int k = kt * 16 + hi * 4;
            float f0 = W[(size_t)(k + 0) * 256 + c];
            float f1 = W[(size_t)(k + 1) * 256 + c];
            float f2 = W[(size_t)(k + 2) * 256 + c];
            float f3 = W[(size_t)(k + 3) * 256 + c];
            half2v p0 = __builtin_amdgcn_cvt_pkrtz(f0, f1);
            half2v p1 = __builtin_amdgcn_cvt_pkrtz(f2, f3);
            aw[mt][kt][0] = p0[0]; aw[mt][kt][1] = p0[1];
            aw[mt][kt][2] = p1[0]; aw[mt][kt][3] = p1[1];
        }
        bv[mt] = *(const float4*)(bias + wbase + mt * 16 + hi * 4);
    }

    half4v xv[4][4];
#pragma unroll
    for (int nt = 0; nt < 4; ++nt) {
        int row = min(r0 + nt * 16 + lo, N - 1);
        const __half* p = x + (size_t)row * 64 + hi * 4;
#pragma unroll
        for (int kt = 0; kt < 4; ++kt)
            xv[nt][kt] = *(const half4v*)(p + kt * 16);
    }

    f32x4 acc[4][4];
#pragma unroll
    for (int mt = 0; mt < 4; ++mt)
#pragma unroll
        for (int nt = 0; nt < 4; ++nt)
            acc[mt][nt] = (f32x4){0.f, 0.f, 0.f, 0.f};

#pragma unroll
    for (int kt = 0; kt < 4; ++kt)
#pragma unroll
        for (int mt = 0; mt < 4; ++mt)
#pragma unroll
            for (int nt = 0; nt < 4; ++nt)
                acc[mt][nt] = __builtin_amdgcn_mfma_f32_16x16x16f16(
                    aw[mt][kt], xv[nt][kt], acc[mt][nt], 0, 0, 0);

    // Epilogue 1: bias + pack + LDS write (swizzled; <=2-way bank aliasing)
#pragma unroll
    for (int nt = 0; nt < 4; ++nt) {
        int row = nt * 16 + lo;                 // 0..63 within tile
#pragma unroll
        for (int mt = 0; mt < 4; ++mt) {
            f32x4 a = acc[mt][nt];
            half2v p0 = __builtin_amdgcn_cvt_pkrtz(a[0] + bv[mt].x, a[1] + bv[mt].y);
            half2v p1 = __builtin_amdgcn_cvt_pkrtz(a[2] + bv[mt].z, a[3] + bv[mt].w);
            union { half2v h[2]; uint2 u; } st;
            st.h[0] = p0; st.h[1] = p1;
            int byte = row * 512 + (wbase + mt * 16 + hi * 4) * 2;
            byte ^= (row & 7) << 4;             // XOR swizzle, bijective/row
            *(uint2*)(lds + byte) = st.u;
        }
    }
    __syncthreads();

    // Epilogue 2: coalesced read-back + 1KB/wave-instr contiguous stores
#pragma unroll
    for (int it = 0; it < 8; ++it) {
        int row = (t >> 5) + it * 8;            // 0..63
        int cb  = (t & 31) * 16;                // byte within row
        int byte = row * 512 + cb;
        byte ^= (row & 7) << 4;
        uint4 v = *(const uint4*)(lds + byte);
        if (r0 + row < N)
            *(uint4*)((unsigned char*)out + (size_t)(r0 + row) * 512 + cb) = v;
    }
}

// ---------------------------------------------------------------------------
// CSR build (self loop at each segment head, +1 folded into scan).
// ---------------------------------------------------------------------------
__global__ void scan_block_kernel(const int* __restrict__ counts, int* __restrict__ excl,
                                  int* __restrict__ blockSums, int N) {
    __shared__ int lds[256];
    int b = blockIdx.x, t = threadIdx.x;
    int base = b * 1024 + t * 4;
    int v0 = (base + 0 < N) ? counts[base + 0] + 1 : 0;
    int v1 = (base + 1 < N) ? counts[base + 1] + 1 : 0;
    int v2 = (base + 2 < N) ? counts[base + 2] + 1 : 0;
    int v3 = (base + 3 < N) ? counts[base + 3] + 1 : 0;
    int s = v0 + v1 + v2 + v3;
    lds[t] = s;
    __syncthreads();
    for (int off = 1; off < 256; off <<= 1) {
        int add = (t >= off) ? lds[t - off] : 0;
        __syncthreads();
        lds[t] += add;
        __syncthreads();
    }
    int run = lds[t] - s;
    if (base + 0 < N) excl[base + 0] = run; run += v0;
    if (base + 1 < N) excl[base + 1] = run; run += v1;
    if (base + 2 < N) excl[base + 2] = run; run += v2;
    if (base + 3 < N) excl[base + 3] = run;
    if (t == 255) blockSums[b] = lds[255];
}

__global__ void finalize_kernel(int* __restrict__ csr_off, const int* __restrict__ blockSums,
                                int* __restrict__ cursor, int* __restrict__ csr_src,
                                int N, int total, int nb) {
    __shared__ int incl[64];
    __shared__ int excl[64];
    int t = threadIdx.x;
    if (t < 64) incl[t] = (t < nb) ? blockSums[t] : 0;
    __syncthreads();
    for (int off = 1; off < 64; off <<= 1) {
        int add = (t >= off && t < 64) ? incl[t - off] : 0;
        __syncthreads();
        if (t < 64) incl[t] += add;
        __syncthreads();
    }
    if (t < 64) excl[t] = t ? incl[t - 1] : 0;
    __syncthreads();

    int i = blockIdx.x * 256 + t;
    if (i < N) {
        int v = csr_off[i] + excl[i >> 10];
        csr_off[i] = v;
        csr_src[v] = i;    // self loop at segment head
        cursor[i]  = v + 1;
    }
    if (i == 0) csr_off[N] = total;
}

__global__ void scatter_kernel(const int* __restrict__ src, const int* __restrict__ dst,
                               int* __restrict__ cursor, int* __restrict__ csr_src, int E) {
    int e = blockIdx.x * 256 + threadIdx.x;
    if (e < E) {
        int pos = atomicAdd(&cursor[dst[e]], 1);
        csr_src[pos] = src[e];
    }
}

// ---------------------------------------------------------------------------
// GATv2 aggregation v7 (best measured). One wave per dst node. Packed-fp16
// logit path (v_pk ops + v_dot2_f32_f16, fp32 accumulate). Degree-adaptive
// flat paths m<=4/8/12/16, rotating 3-buffer pipeline for m>16.
// Measured floor: fill-path-bound (~113MB @ ~2.6TB/s) with VALU ~74%
// hidden beneath. v8 two-edge remap regressed (+4us); fp8 xl failed absmax.
// ---------------------------------------------------------------------------
__global__ __launch_bounds__(256) void agg_kernel(
        const __half* __restrict__ xl, const __half* __restrict__ xr,
        const int* __restrict__ csr_off, const int* __restrict__ csr_src,
        const float* __restrict__ att,   // [4*64] this layer
        const float* __restrict__ gbias, // [64] this layer
        __half* __restrict__ xout, int N, int apply_gelu) {
    int wave = threadIdx.x >> 6;
    int lane = threadIdx.x & 63;
    int n = __builtin_amdgcn_readfirstlane(blockIdx.x * 4 + wave);
    if (n >= N) return;

    union HU { uint2 u; half2v h[2]; };

    float4 attf = ((const float4*)att)[lane];
    half2v att_lo = __builtin_amdgcn_cvt_pkrtz(attf.x * LOG2E, attf.y * LOG2E);
    half2v att_hi = __builtin_amdgcn_cvt_pkrtz(attf.z * LOG2E, attf.w * LOG2E);

    HU xru; xru.u = *(const uint2*)(xr + (size_t)n * 256 + lane * 4);
    half2v xr_lo = xru.h[0], xr_hi = xru.h[1];
    const half2v ns2 = {(__fp16)NEG_SLOPE, (__fp16)NEG_SLOPE};

    int beg  = csr_off[n];       // uniform -> s_load
    int end  = csr_off[n + 1];
    int m    = end - beg;        // includes self loop, >= 1
    int last = end - 1;

    const __half* __restrict__ xlp = xl + lane * 4;

    auto idx4 = [&](int pos) -> int4 {
        if (pos + 3 <= last) {            // uniform branch; aligned-enough
            int4 v;
            __builtin_memcpy(&v, csr_src + pos, 16);
            return v;
        }
        int4 v;
        v.x = csr_src[min(pos,     last)];
        v.y = csr_src[min(pos + 1, last)];
        v.z = csr_src[min(pos + 2, last)];
        v.w = csr_src[min(pos + 3, last)];
        return v;
    };
    auto rows4 = [&](const int4& iv, uint2& r0, uint2& r1, uint2& r2, uint2& r3) {
        r0 = *(const uint2*)(xlp + (size_t)iv.x * 256);
        r1 = *(const uint2*)(xlp + (size_t)iv.y * 256);
        r2 = *(const uint2*)(xlp + (size_t)iv.z * 256);
        r3 = *(const uint2*)(xlp + (size_t)iv.w * 256);
    };
    // packed-fp16 logit: s=xl+xr, leaky, att-dot (fp32 inside v_dot2)
    auto logit = [&](half2v lo, half2v hi) -> float {
        half2v s0 = lo + xr_lo;
        half2v s1 = hi + xr_hi;
        half2v t0 = __builtin_elementwise_max(s0, s0 * ns2);
        half2v t1 = __builtin_elementwise_max(s1, s1 * ns2);
        return FDOT2(t1, att_hi, FDOT2(t0, att_lo, 0.f));
    };

    float ax = 0.f, ay = 0.f, az = 0.f, aw = 0.f, denom = 0.f;

    auto compute4 = [&](const uint2& q0, const uint2& q1, const uint2& q2,
                        const uint2& q3, int kbase) {
        HU e0, e1, e2, e3;
        e0.u = q0; e1.u = q1; e2.u = q2; e3.u = q3;
        float p0 = logit(e0.h[0], e0.h[1]);
        float p1 = logit(e1.h[0], e1.h[1]);
        float p2 = logit(e2.h[0], e2.h[1]);
        float p3 = logit(e3.h[0], e3.h[1]);
        DPP_ADD(p0, 0xB1);  DPP_ADD(p1, 0xB1);  DPP_ADD(p2, 0xB1);  DPP_ADD(p3, 0xB1);
        DPP_ADD(p0, 0x4E);  DPP_ADD(p1, 0x4E);  DPP_ADD(p2, 0x4E);  DPP_ADD(p3, 0x4E);
        DPP_ADD(p0, 0x141); DPP_ADD(p1, 0x141); DPP_ADD(p2, 0x141); DPP_ADD(p3, 0x141);
        DPP_ADD(p0, 0x140); DPP_ADD(p1, 0x140); DPP_ADD(p2, 0x140); DPP_ADD(p3, 0x140);
        float w0 = EXP2(p0);                            // slot 0 always valid
        float w1 = (kbase + 1 < m) ? EXP2(p1) : 0.f;    // branchless tail
        float w2 = (kbase + 2 < m) ? EXP2(p2) : 0.f;
        float w3 = (kbase + 3 < m) ? EXP2(p3) : 0.f;
        denom += (w0 + w1) + (w2 + w3);
        // fp32 accumulate; (float)__fp16 * f32 + f32 folds to v_fma_mix_f32
        ax += w0 * (float)e0.h[0][0] + w1 * (float)e1.h[0][0]
            + w2 * (float)e2.h[0][0] + w3 * (float)e3.h[0][0];
        ay += w0 * (float)e0.h[0][1] + w1 * (float)e1.h[0][1]
            + w2 * (float)e2.h[0][1] + w3 * (float)e3.h[0][1];
        az += w0 * (float)e0.h[1][0] + w1 * (float)e1.h[1][0]
            + w2 * (float)e2.h[1][0] + w3 * (float)e3.h[1][0];
        aw += w0 * (float)e0.h[1][1] + w1 * (float)e1.h[1][1]
            + w2 * (float)e2.h[1][1] + w3 * (float)e3.h[1][1];
    };

    uint2 a0, a1, a2, a3, b0, b1, b2, b3, c0, c1, c2, c3;
    if (m <= 8) {
        rows4(idx4(beg), a0, a1, a2, a3);
        if (m <= 4) {                      // 1 block
            compute4(a0, a1, a2, a3, 0);
        } else {                           // 2 blocks
            rows4(idx4(beg + 4), b0, b1, b2, b3);
            compute4(a0, a1, a2, a3, 0);
            compute4(b0, b1, b2, b3, 4);
        }
    } else if (m <= 16) {
        // flat: issue all indices, then all rows, then compute (no waste)
        int4 i0 = idx4(beg), i1 = idx4(beg + 4), i2 = idx4(beg + 8);
        rows4(i0, a0, a1, a2, a3);
        rows4(i1, b0, b1, b2, b3);
        rows4(i2, c0, c1, c2, c3);
        if (m <= 12) {                     // 3 blocks
            compute4(a0, a1, a2, a3, 0);
            compute4(b0, b1, b2, b3, 4);
            compute4(c0, c1, c2, c3, 8);
        } else {                           // 4 blocks
            uint2 d0, d1, d2, d3;
            rows4(idx4(beg + 12), d0, d1, d2, d3);
            compute4(a0, a1, a2, a3, 0);
            compute4(b0, b1, b2, b3, 4);
            compute4(c0, c1, c2, c3, 8);
            compute4(d0, d1, d2, d3, 12);
        }
    } else {                               // m > 16 (~0.5%): rotating pipeline
        rows4(idx4(beg),     a0, a1, a2, a3);
        rows4(idx4(beg + 4), b0, b1, b2, b3);
        rows4(idx4(beg + 8), c0, c1, c2, c3);
        int4 ja = idx4(beg + 12);
        int4 jb = idx4(beg + 16);
        int4 jc = idx4(beg + 20);
        int g = 0;
        while (true) {
            compute4(a0, a1, a2, a3, g);
            if (g + 4 >= m) break;
            rows4(ja, a0, a1, a2, a3);  ja = idx4(beg + g + 24);

            compute4(b0, b1, b2, b3, g + 4);
            if (g + 8 >= m) break;
            rows4(jb, b0, b1, b2, b3);  jb = idx4(beg + g + 28);

            compute4(c0, c1, c2, c3, g + 8);
            if (g + 12 >= m) break;
            rows4(jc, c0, c1, c2, c3);  jc = idx4(beg + g + 32);

            g += 12;
        }
    }

    float inv = 1.f / denom;
    float rx = ax * inv, ry = ay * inv, rz = az * inv, rw = aw * inv;
    // head mean: lanes j, j^16, j^32, j^48 share feature d
    rx += __shfl_xor(rx, 16); rx += __shfl_xor(rx, 32);
    ry += __shfl_xor(ry, 16); ry += __shfl_xor(ry, 32);
    rz += __shfl_xor(rz, 16); rz += __shfl_xor(rz, 32);
    rw += __shfl_xor(rw, 16); rw += __shfl_xor(rw, 32);

    if (lane < 16) {
        int d0 = lane * 4;
        float4 bvv = *(const float4*)(gbias + d0);
        float ox = 0.25f * rx + bvv.x;
        float oy = 0.25f * ry + bvv.y;
        float oz = 0.25f * rz + bvv.z;
        float ow = 0.25f * rw + bvv.w;
        if (apply_gelu) {
            const float kk = 0.70710678118654752440f;
            ox = 0.5f * ox * (1.f + erff(ox * kk));
            oy = 0.5f * oy * (1.f + erff(oy * kk));
            oz = 0.5f * oz * (1.f + erff(oz * kk));
            ow = 0.5f * ow * (1.f + erff(ow * kk));
        }
        uint2 st = make_uint2(f2h2(ox, oy), f2h2(oz, ow));
        *(uint2*)(xout + (size_t)n * 64 + d0) = st;
    }
}

// ---------------------------------------------------------------------------
// Global mean pool (batch sorted) + classifier. Block per graph, 256 threads.
// ---------------------------------------------------------------------------
__global__ __launch_bounds__(256) void pool_kernel(
        const __half* __restrict__ x, const int* __restrict__ batch,
        const float* __restrict__ Wc, const float* __restrict__ bc,
        float* __restrict__ out, int N, int G) {
    __shared__ float part[4][64];
    __shared__ float pooled[64];
    int g = blockIdx.x, t = threadIdx.x;
    int sub = t >> 6, lane = t & 63;
    int lo = 0, hi = N;
    while (lo < hi) { int mid = (lo + hi) >> 1; if (batch[mid] < g) lo = mid + 1; else hi = mid; }
    int beg = lo;
    hi = N;
    while (lo < hi) { int mid = (lo + hi) >> 1; if (batch[mid] < g + 1) lo = mid + 1; else hi = mid; }
    int end = lo;

    float acc = 0.f;
    for (int n = beg + sub; n < end; n += 4) acc += __half2float(x[(size_t)n * 64 + lane]);
    part[sub][lane] = acc;
    __syncthreads();
    if (t < 64) {
        float s = (part[0][t] + part[1][t]) + (part[2][t] + part[3][t]);
        int cnt = end - beg;
        pooled[t] = (cnt > 0) ? s / (float)cnt : 0.f;
    }
    __syncthreads();
    if (t < 10) {
        float o = bc[t];
        for (int d = 0; d < 64; ++d) o += pooled[d] * Wc[d * 10 + t];
        out[(size_t)g * 10 + t] = o;
    }
}

// ---------------------------------------------------------------------------
extern "C" void kernel_launch(void* const* d_in, const int* in_sizes, int n_in,
                              void* d_out, int out_size, void* d_ws, size_t ws_size,
                              hipStream_t stream) {
    const int*   feat  = (const int*)d_in[0];
    const int*   edges = (const int*)d_in[1];
    const int*   batch = (const int*)d_in[2];
    const float* emb   = (const float*)d_in[3];
    const float* Wl    = (const float*)d_in[4];
    const float* bl    = (const float*)d_in[5];
    const float* Wr    = (const float*)d_in[6];
    const float* br    = (const float*)d_in[7];
    const float* att   = (const float*)d_in[8];
    const float* gb    = (const float*)d_in[9];
    const float* Wc    = (const float*)d_in[10];
    const float* bc    = (const float*)d_in[11];
    float* out = (float*)d_out;

    const int N = in_sizes[2];
    const int E = in_sizes[1] / 2;
    const int G = out_size / 10;

    char* ws = (char*)d_ws;
    size_t off = 0;
    auto alloc = [&](size_t bytes) -> char* {
        char* p = ws + off;
        off = (off + bytes + 255) & ~(size_t)255;
        return p;
    };
    __half* x         = (__half*)alloc((size_t)N * 64 * 2);
    __half* xl        = (__half*)alloc((size_t)N * 256 * 2);
    __half* xr        = (__half*)alloc((size_t)N * 256 * 2);
    int*    counts    = (int*)alloc((size_t)N * 4);
    int*    csr_off   = (int*)alloc((size_t)(N + 8) * 4);
    int*    cursor    = (int*)alloc((size_t)N * 4);
    int*    csr_src   = (int*)alloc((size_t)(E + N + 64) * 4);
    int*    blockSums = (int*)alloc(256 * 4);

    const int* srcv = edges;
    const int* dstv = edges + E;

    // 1) zero counts, fused embed + histogram
    hipMemsetAsync(counts, 0, (size_t)N * 4, stream);
    hipLaunchKernelGGL(embed_kernel, dim3((N + 3) / 4), dim3(256), 0, stream,
                       feat, emb, dstv, counts, x, N, E);

    // 2) CSR by destination, self-loop at each segment head (+1 in scan)
    int nb = (N + 1023) / 1024;
    hipLaunchKernelGGL(scan_block_kernel, dim3(nb), dim3(256), 0, stream, counts, csr_off, blockSums, N);
    hipLaunchKernelGGL(finalize_kernel, dim3((N + 255) / 256), dim3(256), 0, stream,
                       csr_off, blockSums, cursor, csr_src, N, E + N, nb);
    hipLaunchKernelGGL(scatter_kernel, dim3((E + 255) / 256), dim3(256), 0, stream, srcv, dstv, cursor, csr_src, E);

    // 3) GATv2 layers
    int nchunks = (N + 63) / 64;
    for (int l = 0; l < 3; ++l) {
        hipLaunchKernelGGL(gemm_kernel, dim3(nchunks, 2), dim3(256), 0, stream,
                           x, Wl + (size_t)l * 64 * 256, Wr + (size_t)l * 64 * 256,
                           bl + l * 256, br + l * 256, xl, xr, N);
        hipLaunchKernelGGL(agg_kernel, dim3((N + 3) / 4), dim3(256), 0, stream,
                           xl, xr, csr_off, csr_src, att + l * 256, gb + l * 64,
                           x, N, (l < 2) ? 1 : 0);
    }

    // 4) pool + classify
    hipLaunchKernelGGL(pool_kernel, dim3(G), dim3(256), 0, stream, x, batch, Wc, bc, out, N, G);
}